// Round 1
// baseline (476.513 us; speedup 1.0000x reference)
//
#include <hip/hip_runtime.h>
#include <cstdint>

// ---------------------------------------------------------------------------
// AttentionAIC: dual-stream QKV proj + per-head RMSNorm + joint SDPA + out-proj
// B=1, S=2048, S_enc=256, D=1536, H=24, HD=64, T=2304.
// Context output is discarded by the reference -> skip add_q_proj, encoder
// q-rows of attention, and to_add_out entirely.
// Strategy: fp32->bf16 convert, MFMA (16x16x32 bf16) GEMMs w/ fused epilogues,
// flash attention with V stored transposed.
// ---------------------------------------------------------------------------

typedef __attribute__((ext_vector_type(8))) short s16x8;   // 8 x bf16
typedef __attribute__((ext_vector_type(4))) float f32x4;

#define LOG2E 1.4426950408889634f

__device__ __forceinline__ short f2bf(float f) {
  union { float f; uint32_t u; } v; v.f = f;
  uint32_t r = v.u + 0x7FFFu + ((v.u >> 16) & 1u);   // RNE
  return (short)(r >> 16);
}

typedef uint32_t __attribute__((address_space(1)))* gas_u32;
typedef uint32_t __attribute__((address_space(3)))* las_u32;

// async global->LDS, 16B per lane; dest must be wave-uniform base + lane*16
__device__ __forceinline__ void gload_lds16(const short* g, short* l) {
  __builtin_amdgcn_global_load_lds((gas_u32)(g), (las_u32)(l), 16, 0, 0);
}

// ---------------------------------------------------------------------------
// fp32 -> bf16 conversion (8 segments in one launch)
// ---------------------------------------------------------------------------
struct CvtSeg { const float* src; short* dst; int n4; };
struct CvtArgs { CvtSeg s[8]; };

__global__ __launch_bounds__(256) void cvt_bf16_kernel(CvtArgs a) {
  const int stride = gridDim.x * blockDim.x;
  const int tid = blockIdx.x * blockDim.x + threadIdx.x;
  for (int i = 0; i < 8; ++i) {
    const float4* src = (const float4*)a.s[i].src;
    short* dst = a.s[i].dst;
    const int n4 = a.s[i].n4;
    for (int j = tid; j < n4; j += stride) {
      float4 v = src[j];
      short4 o;
      o.x = f2bf(v.x); o.y = f2bf(v.y); o.z = f2bf(v.z); o.w = f2bf(v.w);
      *(short4*)(dst + (size_t)j * 4) = o;
    }
  }
}

// ---------------------------------------------------------------------------
// GEMM: C[M,1536] = A[M,1536] @ W[1536,1536]^T (+bias) with fused epilogues
// 128x128 tile, BK=32, 4 waves (2x2), wave = 64x64 via 4x4 of 16x16x32 MFMA.
// ---------------------------------------------------------------------------
enum { MODE_Q = 0, MODE_K = 1, MODE_V = 2, MODE_OUT = 3 };

struct GemmCfg {
  const short* A;      // [M,1536] bf16
  const short* W;      // [1536,1536] bf16, row-major [N][K]
  const float* bias;   // [1536] fp32
  const float* normw;  // [64] fp32 (Q/K modes)
  void* dst;
  int toff;            // t offset for K/V (0 hidden, 2048 encoder)
  int mode;
};
struct GemmArgs { GemmCfg c[3]; };

__global__ __launch_bounds__(256) void proj_gemm_kernel(GemmArgs args) {
  const GemmCfg cfg = args.c[blockIdx.z];
  constexpr int K = 1536;
  __shared__ short As[4096];  // [128][32]
  __shared__ short Bs[4096];  // [128][32]
  const int t = threadIdx.x;
  const int lane = t & 63;
  const int wave = t >> 6;
  const int l16 = lane & 15;
  const int quad = lane >> 4;
  const int wm = wave >> 1;
  const int wn = wave & 1;

  const short* __restrict__ Ag = cfg.A + (size_t)(blockIdx.y * 128) * K;
  const short* __restrict__ Wg = cfg.W + (size_t)(blockIdx.x * 128) * K;
  const int srow = t >> 2;          // 0..63
  const int scol = (t & 3) << 3;    // 0,8,16,24

  const f32x4 z4 = {0.f, 0.f, 0.f, 0.f};
  f32x4 acc[4][4];
#pragma unroll
  for (int i = 0; i < 4; ++i) {
#pragma unroll
    for (int j = 0; j < 4; ++j) acc[i][j] = z4;
  }

  for (int k0 = 0; k0 < K; k0 += 32) {
    gload_lds16(Ag + (size_t)srow * K + k0 + scol, As + t * 8);
    gload_lds16(Ag + (size_t)(srow + 64) * K + k0 + scol, As + 2048 + t * 8);
    gload_lds16(Wg + (size_t)srow * K + k0 + scol, Bs + t * 8);
    gload_lds16(Wg + (size_t)(srow + 64) * K + k0 + scol, Bs + 2048 + t * 8);
    __syncthreads();
    s16x8 af[4], bfr[4];
#pragma unroll
    for (int i = 0; i < 4; ++i)
      af[i] = *(const s16x8*)(As + (wm * 64 + i * 16 + l16) * 32 + quad * 8);
#pragma unroll
    for (int i = 0; i < 4; ++i)
      bfr[i] = *(const s16x8*)(Bs + (wn * 64 + i * 16 + l16) * 32 + quad * 8);
#pragma unroll
    for (int mi = 0; mi < 4; ++mi) {
#pragma unroll
      for (int ni = 0; ni < 4; ++ni)
        acc[mi][ni] = __builtin_amdgcn_mfma_f32_16x16x32_bf16(af[mi], bfr[ni], acc[mi][ni], 0, 0, 0);
    }
    __syncthreads();
  }

  // epilogue: C/D layout col=lane&15, row=quad*4+reg
  const int nbase = blockIdx.x * 128 + wn * 64;   // 64-aligned -> one head/wave
  const int mbase = blockIdx.y * 128 + wm * 64;
  const int mode = cfg.mode;
  const int h = nbase >> 6;

  float biasv[4], nwv[4];
#pragma unroll
  for (int ni = 0; ni < 4; ++ni) {
    int col = nbase + ni * 16 + l16;
    biasv[ni] = cfg.bias[col];
    nwv[ni] = (mode == MODE_Q || mode == MODE_K) ? cfg.normw[col & 63] : 0.f;
  }

#pragma unroll
  for (int mi = 0; mi < 4; ++mi) {
    float vv[4][4];
#pragma unroll
    for (int ni = 0; ni < 4; ++ni) {
#pragma unroll
      for (int r = 0; r < 4; ++r) vv[ni][r] = acc[mi][ni][r] + biasv[ni];
    }
    if (mode == MODE_Q || mode == MODE_K) {
      // RMSNorm over the head (this wave's 64 cols): reduce ni then 16 lanes
      float ss[4];
#pragma unroll
      for (int r = 0; r < 4; ++r)
        ss[r] = vv[0][r] * vv[0][r] + vv[1][r] * vv[1][r] +
                vv[2][r] * vv[2][r] + vv[3][r] * vv[3][r];
#pragma unroll
      for (int r = 0; r < 4; ++r) {
        ss[r] += __shfl_xor(ss[r], 1);
        ss[r] += __shfl_xor(ss[r], 2);
        ss[r] += __shfl_xor(ss[r], 4);
        ss[r] += __shfl_xor(ss[r], 8);
        float rs = rsqrtf(ss[r] * (1.0f / 64.0f) + 1e-6f);
#pragma unroll
        for (int ni = 0; ni < 4; ++ni) vv[ni][r] *= rs * nwv[ni];
      }
    }
    const int row0 = mbase + mi * 16 + quad * 4;  // + r
    if (mode == MODE_Q) {
      short* Qd = (short*)cfg.dst;  // [24][2048][64]
#pragma unroll
      for (int ni = 0; ni < 4; ++ni) {
        int d = ni * 16 + l16;
#pragma unroll
        for (int r = 0; r < 4; ++r)
          Qd[((size_t)h * 2048 + row0 + r) * 64 + d] = f2bf(vv[ni][r]);
      }
    } else if (mode == MODE_K) {
      short* Kd = (short*)cfg.dst;  // [24][2304][64]
#pragma unroll
      for (int ni = 0; ni < 4; ++ni) {
        int d = ni * 16 + l16;
#pragma unroll
        for (int r = 0; r < 4; ++r)
          Kd[((size_t)h * 2304 + cfg.toff + row0 + r) * 64 + d] = f2bf(vv[ni][r]);
      }
    } else if (mode == MODE_V) {
      short* Vd = (short*)cfg.dst;  // V^T: [24][64][2304]
#pragma unroll
      for (int ni = 0; ni < 4; ++ni) {
        int d = ni * 16 + l16;
        short4 o4;
        o4.x = f2bf(vv[ni][0]); o4.y = f2bf(vv[ni][1]);
        o4.z = f2bf(vv[ni][2]); o4.w = f2bf(vv[ni][3]);
        *(short4*)(Vd + ((size_t)h * 64 + d) * 2304 + cfg.toff + row0) = o4;
      }
    } else {  // MODE_OUT: fp32 row-major [2048][1536]
      float* Od = (float*)cfg.dst;
#pragma unroll
      for (int ni = 0; ni < 4; ++ni) {
        int col = nbase + ni * 16 + l16;
#pragma unroll
        for (int r = 0; r < 4; ++r)
          Od[(size_t)(row0 + r) * 1536 + col] = vv[ni][r];
      }
    }
  }
}

// ---------------------------------------------------------------------------
// Flash attention: block = (q-tile of 64, head); 4 waves, 16 q-rows each.
// K tiles of 64. Q/K in [H][T][64], V in [H][64][T] (transposed).
// Only q < 2048 computed (context output unused).
// ---------------------------------------------------------------------------
__global__ __launch_bounds__(256) void flash_kernel(
    const short* __restrict__ Q, const short* __restrict__ Kc,
    const short* __restrict__ VT, const float* __restrict__ mask,
    short* __restrict__ AO) {
  const int h = blockIdx.y;
  const int lane = threadIdx.x & 63;
  const int wave = threadIdx.x >> 6;
  const int l16 = lane & 15;
  const int quad = lane >> 4;
  const int q0 = blockIdx.x * 64 + wave * 16;

  __shared__ short Pl[4][1024];   // per-wave 16x64 P tile, XOR-swizzled blocks
  short* Pw = &Pl[wave][0];

  const short* Qrow = Q + ((size_t)h * 2048 + q0 + l16) * 64;
  s16x8 aq0 = *(const s16x8*)(Qrow + quad * 8);
  s16x8 aq1 = *(const s16x8*)(Qrow + quad * 8 + 32);

  const f32x4 z4 = {0.f, 0.f, 0.f, 0.f};
  f32x4 o[4] = {z4, z4, z4, z4};
  float m_r[4] = {-1e30f, -1e30f, -1e30f, -1e30f};
  float l_r[4] = {0.f, 0.f, 0.f, 0.f};

  const short* Kh = Kc + (size_t)h * 2304 * 64;
  const short* Vh = VT + (size_t)h * 64 * 2304;

  for (int kb = 0; kb < 2304; kb += 64) {
    f32x4 s[4];
#pragma unroll
    for (int ni = 0; ni < 4; ++ni) {
      const short* Krow = Kh + (size_t)(kb + ni * 16 + l16) * 64;
      f32x4 p0 = __builtin_amdgcn_mfma_f32_16x16x32_bf16(
          aq0, *(const s16x8*)(Krow + quad * 8), z4, 0, 0, 0);
      s[ni] = __builtin_amdgcn_mfma_f32_16x16x32_bf16(
          aq1, *(const s16x8*)(Krow + quad * 8 + 32), p0, 0, 0, 0);
      float mv = mask[kb + ni * 16 + l16];
#pragma unroll
      for (int r = 0; r < 4; ++r) s[ni][r] = fmaf(s[ni][r], 0.125f, mv);
    }
    // row max across 64 cols (4 frags x 16 lanes of the quad group)
    float tm[4];
#pragma unroll
    for (int r = 0; r < 4; ++r)
      tm[r] = fmaxf(fmaxf(s[0][r], s[1][r]), fmaxf(s[2][r], s[3][r]));
#pragma unroll
    for (int r = 0; r < 4; ++r) {
      tm[r] = fmaxf(tm[r], __shfl_xor(tm[r], 1));
      tm[r] = fmaxf(tm[r], __shfl_xor(tm[r], 2));
      tm[r] = fmaxf(tm[r], __shfl_xor(tm[r], 4));
      tm[r] = fmaxf(tm[r], __shfl_xor(tm[r], 8));
    }
    float alpha[4];
#pragma unroll
    for (int r = 0; r < 4; ++r) {
      float mn = fmaxf(m_r[r], tm[r]);
      alpha[r] = exp2f((m_r[r] - mn) * LOG2E);
      m_r[r] = mn;
    }
    float ps[4] = {0.f, 0.f, 0.f, 0.f};
#pragma unroll
    for (int ni = 0; ni < 4; ++ni) {
      int pcol = ni * 16 + l16;
      int cb = pcol >> 3;
#pragma unroll
      for (int r = 0; r < 4; ++r) {
        float p = exp2f((s[ni][r] - m_r[r]) * LOG2E);
        ps[r] += p;
        int prow = quad * 4 + r;
        Pw[prow * 64 + ((cb ^ (prow & 7)) << 3) + (pcol & 7)] = f2bf(p);
      }
    }
#pragma unroll
    for (int r = 0; r < 4; ++r) {
      ps[r] += __shfl_xor(ps[r], 1);
      ps[r] += __shfl_xor(ps[r], 2);
      ps[r] += __shfl_xor(ps[r], 4);
      ps[r] += __shfl_xor(ps[r], 8);
      l_r[r] = l_r[r] * alpha[r] + ps[r];
    }
#pragma unroll
    for (int ni = 0; ni < 4; ++ni) {
#pragma unroll
      for (int r = 0; r < 4; ++r) o[ni][r] *= alpha[r];
    }
    // P: C-layout -> A-operand layout via per-wave LDS (swizzled, no barrier)
    s16x8 ap0 = *(const s16x8*)(Pw + l16 * 64 + ((quad ^ (l16 & 7)) << 3));
    s16x8 ap1 = *(const s16x8*)(Pw + l16 * 64 + (((quad + 4) ^ (l16 & 7)) << 3));
#pragma unroll
    for (int ni = 0; ni < 4; ++ni) {
      const short* Vrow = Vh + (size_t)(ni * 16 + l16) * 2304 + kb;
      o[ni] = __builtin_amdgcn_mfma_f32_16x16x32_bf16(
          ap0, *(const s16x8*)(Vrow + quad * 8), o[ni], 0, 0, 0);
      o[ni] = __builtin_amdgcn_mfma_f32_16x16x32_bf16(
          ap1, *(const s16x8*)(Vrow + quad * 8 + 32), o[ni], 0, 0, 0);
    }
  }
#pragma unroll
  for (int r = 0; r < 4; ++r) {
    float inv = 1.0f / l_r[r];
    int tq = q0 + quad * 4 + r;
#pragma unroll
    for (int ni = 0; ni < 4; ++ni)
      AO[(size_t)tq * 1536 + h * 64 + ni * 16 + l16] = f2bf(o[ni][r] * inv);
  }
}

// ---------------------------------------------------------------------------
extern "C" void kernel_launch(void* const* d_in, const int* in_sizes, int n_in,
                              void* d_out, int out_size, void* d_ws, size_t ws_size,
                              hipStream_t stream) {
  (void)in_sizes; (void)n_in; (void)out_size; (void)ws_size;
  const float* hidden = (const float*)d_in[0];
  const float* enc    = (const float*)d_in[1];
  const float* amask  = (const float*)d_in[2];
  const float* wq  = (const float*)d_in[3];  const float* bq  = (const float*)d_in[4];
  const float* wk  = (const float*)d_in[5];  const float* bk  = (const float*)d_in[6];
  const float* wv  = (const float*)d_in[7];  const float* bv  = (const float*)d_in[8];
  const float* nqw = (const float*)d_in[9];  const float* nkw = (const float*)d_in[10];
  // d_in[11],[12],[17]: add_q_proj + norm_added_q -> dead (context q unused)
  const float* wak = (const float*)d_in[13]; const float* bak = (const float*)d_in[14];
  const float* wav = (const float*)d_in[15]; const float* bav = (const float*)d_in[16];
  const float* nakw = (const float*)d_in[18];
  const float* wo  = (const float*)d_in[19]; const float* bo  = (const float*)d_in[20];
  // d_in[21],[22]: to_add_out -> dead
  float* out = (float*)d_out;

  char* p = (char*)d_ws;
  auto carve = [&](size_t bytes) { char* r = p; p += (bytes + 255) & ~(size_t)255; return r; };
  short* Xb   = (short*)carve((size_t)2048 * 1536 * 2);
  short* Eb   = (short*)carve((size_t)256 * 1536 * 2);
  short* Wqb  = (short*)carve((size_t)1536 * 1536 * 2);
  short* Wkb  = (short*)carve((size_t)1536 * 1536 * 2);
  short* Wvb  = (short*)carve((size_t)1536 * 1536 * 2);
  short* Wakb = (short*)carve((size_t)1536 * 1536 * 2);
  short* Wavb = (short*)carve((size_t)1536 * 1536 * 2);
  short* Wob  = (short*)carve((size_t)1536 * 1536 * 2);
  short* Qb   = (short*)carve((size_t)24 * 2048 * 64 * 2);
  short* Kb   = (short*)carve((size_t)24 * 2304 * 64 * 2);
  short* VTb  = (short*)carve((size_t)24 * 64 * 2304 * 2);
  short* AOb  = (short*)carve((size_t)2048 * 1536 * 2);

  CvtArgs ca;
  ca.s[0] = {hidden, Xb, 2048 * 1536 / 4};
  ca.s[1] = {enc,    Eb, 256 * 1536 / 4};
  ca.s[2] = {wq,  Wqb,  1536 * 1536 / 4};
  ca.s[3] = {wk,  Wkb,  1536 * 1536 / 4};
  ca.s[4] = {wv,  Wvb,  1536 * 1536 / 4};
  ca.s[5] = {wak, Wakb, 1536 * 1536 / 4};
  ca.s[6] = {wav, Wavb, 1536 * 1536 / 4};
  ca.s[7] = {wo,  Wob,  1536 * 1536 / 4};
  cvt_bf16_kernel<<<dim3(1024), dim3(256), 0, stream>>>(ca);

  GemmArgs g1;  // hidden-stream Q,K,V (fused via blockIdx.z)
  g1.c[0] = {Xb, Wqb, bq, nqw, (void*)Qb,  0, MODE_Q};
  g1.c[1] = {Xb, Wkb, bk, nkw, (void*)Kb,  0, MODE_K};
  g1.c[2] = {Xb, Wvb, bv, nullptr, (void*)VTb, 0, MODE_V};
  proj_gemm_kernel<<<dim3(12, 16, 3), dim3(256), 0, stream>>>(g1);

  GemmArgs g2;  // encoder-stream K,V into rows [2048,2304)
  g2.c[0] = {Eb, Wakb, bak, nakw, (void*)Kb,  2048, MODE_K};
  g2.c[1] = {Eb, Wavb, bav, nullptr, (void*)VTb, 2048, MODE_V};
  g2.c[2] = g2.c[0];
  proj_gemm_kernel<<<dim3(12, 2, 2), dim3(256), 0, stream>>>(g2);

  flash_kernel<<<dim3(32, 24), dim3(256), 0, stream>>>(Qb, Kb, VTb, amask, AOb);

  GemmArgs g3;  // out projection -> fp32 d_out
  g3.c[0] = {AOb, Wob, bo, nullptr, (void*)out, 0, MODE_OUT};
  g3.c[1] = g3.c[0];
  g3.c[2] = g3.c[0];
  proj_gemm_kernel<<<dim3(12, 16, 1), dim3(256), 0, stream>>>(g3);
}